// Round 1
// baseline (1032.791 us; speedup 1.0000x reference)
//
#include <hip/hip_runtime.h>
#include <math.h>

typedef unsigned short u16;
typedef __attribute__((ext_vector_type(4))) float f32x4;
typedef __attribute__((ext_vector_type(8))) __bf16 bf16x8;
typedef __attribute__((ext_vector_type(8))) u16 u16x8;
typedef __attribute__((ext_vector_type(4))) u16 u16x4;

__device__ __forceinline__ float bf2f(u16 v) {
    unsigned int u = ((unsigned int)v) << 16;
    return __builtin_bit_cast(float, u);
}
__device__ __forceinline__ u16 f2bf(float f) {
    unsigned int x = __builtin_bit_cast(unsigned int, f);
    x += 0x7fffu + ((x >> 16) & 1u);   // RNE
    return (u16)(x >> 16);
}

__device__ __forceinline__ void load_lds16(const u16* g, u16* l) {
    __builtin_amdgcn_global_load_lds((const __attribute__((address_space(1))) void*)g,
                                     (__attribute__((address_space(3))) void*)l, 16, 0, 0);
}

#define WAIT_VM(N) asm volatile("s_waitcnt vmcnt(" #N ")" ::: "memory")
#define MFMA16(d, x, y) d = __builtin_amdgcn_mfma_f32_16x16x32_bf16(x, y, d, 0, 0, 0)

__device__ __forceinline__ void phase_barrier() {
    __builtin_amdgcn_sched_barrier(0);
    asm volatile("" ::: "memory");
    __builtin_amdgcn_s_barrier();
    asm volatile("" ::: "memory");
    __builtin_amdgcn_sched_barrier(0);
}

// ---------------------------------------------------------------------------
// f32 -> bf16 weight conversion
// ---------------------------------------------------------------------------
__global__ __launch_bounds__(256) void cvt_kernel(const float* __restrict__ in,
                                                  u16* __restrict__ out, int n)
{
    const int i = (blockIdx.x * 256 + threadIdx.x) * 4;
    if (i >= n) return;
    const float4 f = *(const float4*)(in + i);
    u16x4 o;
    o[0] = f2bf(f.x); o[1] = f2bf(f.y); o[2] = f2bf(f.z); o[3] = f2bf(f.w);
    *(u16x4*)(out + i) = o;
}

// ---------------------------------------------------------------------------
// 256x256 8-phase GEMM: C[M][N] = epi( A[M][K](bf16) * W[N][K](bf16)^T + bias )
//
// Schedule (per BK=64 K-tile, 4 phases, 16 MFMA each):
//   P0: ds_read a0[8](k0) + b(nf0,nf1;k0); issue next-tile A0,A1; MFMA; bar
//   P1: ds_read a1[8](k1) + b(nf0,nf1;k1); issue next B0;  MFMA; vmcnt(6); bar
//   P2: ds_read b(nf2,nf3;k0);             issue next B1;  MFMA; bar
//   P3: ds_read b(nf2,nf3;k1);                             MFMA; vmcnt(2); bar
// Counted-vmcnt invariant at tile entry: halves A0,A1,B0 of tile t complete,
// B1 (2 loads) still in flight -> drained by P1's vmcnt(6). Never vmcnt(0)
// except the final tile. Raw s_barrier (no implicit drain).
//
// LDS 128 KiB: [buf 2][ A 256x64 | B 256x64 ] bf16, linear rows of 128 B.
// T2 swizzle: element (r,c-seg s) stored at seg s^(r&7); achieved by
// pre-swizzling the GLOBAL source column per lane (linear LDS dest), and
// XOR-ing the ds_read col the same way -> conflict-free b128 reads.
// B rows are PERMUTED in LDS (n-half-major) so each phase's B-half is a
// contiguous 16 KB staging chunk, enabling in-order half consumption.
//
// EPI 0: qkv scatter -> Q (bh,t,d), K (bh,t,d), Vt (bh,d,t)
// EPI 1: + residual (RES=1 f32, RES=2 bf16); EPI 2: exact GELU
// OF32: O0 is float* (final output); else u16* (bf16)
// ---------------------------------------------------------------------------
template<int EPI, int RES, bool OF32>
__global__ __launch_bounds__(512, 2) void gemm256(
    const u16* __restrict__ A, const u16* __restrict__ W,
    const float* __restrict__ bias,
    const float* __restrict__ resf, const u16* __restrict__ resb,
    void* __restrict__ O0v, u16* __restrict__ O1, u16* __restrict__ O2,
    int M, int N, int K, int mbase)
{
    __shared__ u16 S[65536];              // 128 KiB
    const int tid  = threadIdx.x;
    const int w    = tid >> 6;
    const int l    = tid & 63;
    const int colq = l & 15;
    const int quad = l >> 4;
    const int w3   = w & 3;
    const int wm   = (w >> 2) * 128;      // wave M offset (2 wave-rows)
    const int wn   = w3 * 64;             // wave N offset (4 wave-cols)

    // T1: XCD-aware bijective block swizzle (all launches have nwg % 8 == 0)
    const int nX  = (int)gridDim.x;
    const int nwg = nX * (int)gridDim.y;
    const int did = (int)blockIdx.y * nX + (int)blockIdx.x;
    const int q8  = nwg >> 3;
    const int wg  = (nwg & 7) ? did : ((did & 7) * q8 + (did >> 3));
    const int bm  = wg / nX;
    const int bn  = wg - bm * nX;
    const int m0  = bm * 256, n0 = bn * 256;

    // -------- staging descriptors (per thread: 8 x 16B loads per K-tile) ----
    const int rw   = l >> 3;                      // row within 8-row group
    const int sseg = ((l & 7) ^ rw) * 8;          // pre-swizzled global col (u16)
    const u16* gA[2][2];
    const u16* gB[2][2];
#pragma unroll
    for (int h = 0; h < 2; ++h)
#pragma unroll
        for (int j = 0; j < 2; ++j) {
            const int rr = (w * 2 + j) * 8 + rw;  // LDS row within half (0..127)
            gA[h][j] = A + (size_t)(m0 + h * 128 + rr) * K + sseg;
            // B LDS row L = h*128 + rr maps to global n:
            const int nl = (rr >> 5) * 64 + (h * 2 + ((rr >> 4) & 1)) * 16 + (rr & 15);
            gB[h][j] = W + (size_t)(n0 + nl) * K + sseg;
        }
    const int lw = w * 1024;                      // LDS stage base per wave (u16)

    // -------- fragment read offsets (u16 units) ----------------------------
    const int c0   = (quad * 8) ^ ((colq & 7) << 3);   // kstep0 col (swizzled)
    const int c1   = c0 ^ 32;                          // kstep1 col
    const int aoff = (wm + colq) * 64;                 // A frag row base
    const int boff = 16384 + (w3 * 32 + colq) * 64;    // B frag row base (nh=0)

    f32x4 acc[8][4] = {};
    bf16x8 a0[8], a1[8], b0, b1;

    // -------- prologue: stage tile 0 (A0,A1,B0,B1), counted drain ----------
#pragma unroll
    for (int h = 0; h < 2; ++h)
#pragma unroll
        for (int j = 0; j < 2; ++j)
            load_lds16(gA[h][j], S + h * 8192 + lw + j * 512);
#pragma unroll
    for (int h = 0; h < 2; ++h)
#pragma unroll
        for (int j = 0; j < 2; ++j)
            load_lds16(gB[h][j], S + 16384 + h * 8192 + lw + j * 512);
    WAIT_VM(2);                 // A0,A1,B0 resident; B1 in flight
    phase_barrier();

    const int NT = K >> 6;
    for (int t = 0; t < NT; ++t) {
        u16* Sc = S + ((t & 1) << 15);
        u16* Sn = S + (((t + 1) & 1) << 15);
        const int  kk = (t + 1) << 6;
        const bool pf = (t + 1) < NT;

        // ---- P0: kstep0 x n-frags {0,1} ----
#pragma unroll
        for (int mf = 0; mf < 8; ++mf)
            a0[mf] = *(const bf16x8*)(Sc + aoff + mf * 1024 + c0);
        b0 = *(const bf16x8*)(Sc + boff + c0);
        b1 = *(const bf16x8*)(Sc + boff + 1024 + c0);
        if (pf) {
#pragma unroll
            for (int h = 0; h < 2; ++h)
#pragma unroll
                for (int j = 0; j < 2; ++j)
                    load_lds16(gA[h][j] + kk, Sn + h * 8192 + lw + j * 512);
        }
        __builtin_amdgcn_s_setprio(1);
#pragma unroll
        for (int mf = 0; mf < 8; ++mf) { MFMA16(acc[mf][0], a0[mf], b0); MFMA16(acc[mf][1], a0[mf], b1); }
        __builtin_amdgcn_s_setprio(0);
        phase_barrier();

        // ---- P1: kstep1 x n-frags {0,1} ----
#pragma unroll
        for (int mf = 0; mf < 8; ++mf)
            a1[mf] = *(const bf16x8*)(Sc + aoff + mf * 1024 + c1);
        b0 = *(const bf16x8*)(Sc + boff + c1);
        b1 = *(const bf16x8*)(Sc + boff + 1024 + c1);
        if (pf) {
#pragma unroll
            for (int j = 0; j < 2; ++j)
                load_lds16(gB[0][j] + kk, Sn + 16384 + lw + j * 512);
        }
        __builtin_amdgcn_s_setprio(1);
#pragma unroll
        for (int mf = 0; mf < 8; ++mf) { MFMA16(acc[mf][0], a1[mf], b0); MFMA16(acc[mf][1], a1[mf], b1); }
        __builtin_amdgcn_s_setprio(0);
        if (pf) { WAIT_VM(6); } else { WAIT_VM(0); }   // drain this tile's B1
        phase_barrier();

        // ---- P2: kstep0 x n-frags {2,3} (B LDS rows 128..255) ----
        b0 = *(const bf16x8*)(Sc + boff + 8192 + c0);
        b1 = *(const bf16x8*)(Sc + boff + 8192 + 1024 + c0);
        if (pf) {
#pragma unroll
            for (int j = 0; j < 2; ++j)
                load_lds16(gB[1][j] + kk, Sn + 16384 + 8192 + lw + j * 512);
        }
        __builtin_amdgcn_s_setprio(1);
#pragma unroll
        for (int mf = 0; mf < 8; ++mf) { MFMA16(acc[mf][2], a0[mf], b0); MFMA16(acc[mf][3], a0[mf], b1); }
        __builtin_amdgcn_s_setprio(0);
        phase_barrier();

        // ---- P3: kstep1 x n-frags {2,3} ----
        b0 = *(const bf16x8*)(Sc + boff + 8192 + c1);
        b1 = *(const bf16x8*)(Sc + boff + 8192 + 1024 + c1);
        __builtin_amdgcn_s_setprio(1);
#pragma unroll
        for (int mf = 0; mf < 8; ++mf) { MFMA16(acc[mf][2], a1[mf], b0); MFMA16(acc[mf][3], a1[mf], b1); }
        __builtin_amdgcn_s_setprio(0);
        if (pf) { WAIT_VM(2); }   // next tile's A0,A1,B0 resident; B1 stays in flight
        phase_barrier();
    }

    // -------- epilogue: C row = quad*4+i, col = colq (m89-verified) --------
#pragma unroll
    for (int nf = 0; nf < 4; ++nf) {
        const int c = n0 + wn + nf * 16 + colq;
        const float bz = bias[c];
#pragma unroll
        for (int mf = 0; mf < 8; ++mf) {
#pragma unroll
            for (int i = 0; i < 4; ++i) {
                const int r = m0 + wm + mf * 16 + quad * 4 + i;
                float v = acc[mf][nf][i] + bz;
                if constexpr (EPI == 0) {
                    const int which = c >> 10;          // (3, h, hd) split of 3C axis
                    const int head  = (c >> 6) & 15;
                    const int d     = c & 63;
                    const int rg    = mbase + r;
                    const int bb    = rg >> 12;
                    const int tt    = rg & 4095;
                    const int bh    = bb * 16 + head;
                    const u16 val = f2bf(v);
                    if (which == 0)      ((u16*)O0v)[((size_t)bh * 4096 + tt) * 64 + d] = val; // Q
                    else if (which == 1) O1[((size_t)bh * 4096 + tt) * 64 + d] = val;          // K
                    else                 O2[((size_t)bh * 64 + d) * 4096 + tt] = val;          // Vt
                } else {
                    const size_t idx = (size_t)r * N + c;
                    if constexpr (RES == 1) v += resf[idx];
                    if constexpr (RES == 2) v += bf2f(resb[idx]);
                    if constexpr (EPI == 2) v = 0.5f * v * (1.0f + erff(v * 0.70710678118654752f));
                    if constexpr (OF32) ((float*)O0v)[idx] = v;
                    else                ((u16*)O0v)[idx] = f2bf(v);
                }
            }
        }
    }
}

// ---------------------------------------------------------------------------
// LayerNorm: one wave per row of 1024. F32IN: x is f32 (LN1); else bf16 (LN2).
// ---------------------------------------------------------------------------
template<bool F32IN>
__global__ __launch_bounds__(256) void ln_kernel(
    const void* __restrict__ xin, const float* __restrict__ w,
    const float* __restrict__ b, u16* __restrict__ out)
{
    const int wave = threadIdx.x >> 6, lane = threadIdx.x & 63;
    const size_t row = (size_t)blockIdx.x * 4 + wave;
    float v[16];
    if constexpr (F32IN) {
        const float* xr = (const float*)xin + row * 1024 + lane * 16;
#pragma unroll
        for (int j = 0; j < 4; ++j) {
            const float4 f = *(const float4*)(xr + j * 4);
            v[j * 4 + 0] = f.x; v[j * 4 + 1] = f.y; v[j * 4 + 2] = f.z; v[j * 4 + 3] = f.w;
        }
    } else {
        const u16* xr = (const u16*)xin + row * 1024 + lane * 16;
        u16x8 xa = *(const u16x8*)xr;
        u16x8 xb = *(const u16x8*)(xr + 8);
#pragma unroll
        for (int i = 0; i < 8; ++i) { v[i] = bf2f(xa[i]); v[8 + i] = bf2f(xb[i]); }
    }
    float s = 0.f, s2 = 0.f;
#pragma unroll
    for (int i = 0; i < 16; ++i) { s += v[i]; s2 += v[i] * v[i]; }
#pragma unroll
    for (int m = 32; m >= 1; m >>= 1) { s += __shfl_xor(s, m, 64); s2 += __shfl_xor(s2, m, 64); }
    const float mu  = s * (1.0f / 1024.0f);
    const float var = s2 * (1.0f / 1024.0f) - mu * mu;
    const float rs  = rsqrtf(var + 1e-5f);
    const float* wp = w + lane * 16;
    const float* bp = b + lane * 16;
    u16x8 oa, ob;
#pragma unroll
    for (int i = 0; i < 8; ++i) {
        oa[i] = f2bf((v[i]     - mu) * rs * wp[i]     + bp[i]);
        ob[i] = f2bf((v[8 + i] - mu) * rs * wp[8 + i] + bp[8 + i]);
    }
    u16* orow = out + row * 1024 + lane * 16;
    *(u16x8*)orow       = oa;
    *(u16x8*)(orow + 8) = ob;
}

// ---------------------------------------------------------------------------
// Local attention, flash-style over 2 key-chunks of 192. (unchanged)
// ---------------------------------------------------------------------------
__global__ __launch_bounds__(256, 4) void attn_kernel(
    const u16* __restrict__ Q, const u16* __restrict__ Kb,
    const u16* __restrict__ Vt, u16* __restrict__ out)
{
    __shared__ u16 Ps[4][16 * 200];
    const int tid  = threadIdx.x;
    const int wave = tid >> 6;
    const int lane = tid & 63;
    const int colq = lane & 15;
    const int quad = lane >> 4;

    const int f   = blockIdx.x;            // 0..4095
    const int xcd = f & 7;
    const int s8  = f >> 3;                // 0..511
    const int bh  = s8 >> 3;               // 0..63
    const int tb  = (s8 & 7) + 8 * xcd;    // 0..63
    const int qrow0 = tb * 64 + wave * 16;
    const int nb    = tb >> 1;
    const int key0  = nb * 128 - 128;
    const int nt_lo = (nb == 0) ? 8 : 0;
    const int nt_hi = (nb == 31) ? 16 : 24;

    const u16* qp = Q + ((size_t)bh * 4096 + qrow0 + colq) * 64 + quad * 8;
    bf16x8 aq0 = *(const bf16x8*)qp;
    bf16x8 aq1 = *(const bf16x8*)(qp + 32);

    float m_i[4], l_i[4];
    f32x4 o[4] = {};
#pragma unroll
    for (int i = 0; i < 4; ++i) { m_i[i] = -3.0e38f; l_i[i] = 0.f; }

    u16* Psw = &Ps[wave][0];

#pragma unroll
    for (int c = 0; c < 2; ++c) {
        const int lo = (c == 0) ? nt_lo : 12;
        const int hi = (c == 0) ? ((nt_hi < 12) ? nt_hi : 12) : nt_hi;

        f32x4 sc[12];
#pragma unroll
        for (int j = 0; j < 12; ++j) sc[j] = (f32x4){0.f, 0.f, 0.f, 0.f};
#pragma unroll
        for (int j = 0; j < 12; ++j) {
            const int nt = c * 12 + j;
            if (nt >= lo && nt < hi) {
                const u16* kp = Kb + ((size_t)bh * 4096 + key0 + nt * 16 + colq) * 64 + quad * 8;
                bf16x8 b0 = *(const bf16x8*)kp;
                bf16x8 b1 = *(const bf16x8*)(kp + 32);
                f32x4 z = {0.f, 0.f, 0.f, 0.f};
                z = __builtin_amdgcn_mfma_f32_16x16x32_bf16(aq0, b0, z, 0, 0, 0);
                z = __builtin_amdgcn_mfma_f32_16x16x32_bf16(aq1, b1, z, 0, 0, 0);
                sc[j] = z;
            }
        }
        float mc[4];
#pragma unroll
        for (int i = 0; i < 4; ++i) mc[i] = -3.0e38f;
#pragma unroll
        for (int j = 0; j < 12; ++j) {
            const int nt = c * 12 + j;
            if (nt >= lo && nt < hi)
#pragma unroll
                for (int i = 0; i < 4; ++i) mc[i] = fmaxf(mc[i], sc[j][i]);
        }
#pragma unroll
        for (int i = 0; i < 4; ++i)
#pragma unroll
            for (int m = 8; m >= 1; m >>= 1) mc[i] = fmaxf(mc[i], __shfl_xor(mc[i], m, 64));
        float a_i[4], psum[4];
#pragma unroll
        for (int i = 0; i < 4; ++i) {
            const float mn = fmaxf(m_i[i], mc[i]);
            a_i[i] = __expf((m_i[i] - mn) * 0.125f);
            m_i[i] = mn;
            psum[i] = 0.f;
        }
#pragma unroll
        for (int j = 0; j < 12; ++j) {
            const int nt = c * 12 + j;
            if (nt >= lo && nt < hi) {
#pragma unroll
                for (int i = 0; i < 4; ++i) {
                    const float p = __expf((sc[j][i] - m_i[i]) * 0.125f);
                    psum[i] += p;
                    Psw[(quad * 4 + i) * 200 + j * 16 + colq] = f2bf(p);
                }
            }
        }
#pragma unroll
        for (int i = 0; i < 4; ++i)
#pragma unroll
            for (int m = 8; m >= 1; m >>= 1) psum[i] += __shfl_xor(psum[i], m, 64);
#pragma unroll
        for (int i = 0; i < 4; ++i) l_i[i] = l_i[i] * a_i[i] + psum[i];
#pragma unroll
        for (int dt = 0; dt < 4; ++dt)
#pragma unroll
            for (int i = 0; i < 4; ++i) o[dt][i] *= a_i[i];
        const int klo = (lo - c * 12) >> 1;
        const int khi = (hi - c * 12) >> 1;
#pragma unroll
        for (int k6 = 0; k6 < 6; ++k6) {
            if (k6 >= klo && k6 < khi) {
                bf16x8 ap = *(const bf16x8*)(Psw + colq * 200 + k6 * 32 + quad * 8);
                const int kkk = key0 + (c * 6 + k6) * 32 + quad * 8;
#pragma unroll
                for (int dt = 0; dt < 4; ++dt) {
                    const u16* vp = Vt + ((size_t)bh * 64 + dt * 16 + colq) * 4096 + kkk;
                    bf16x8 bv = *(const bf16x8*)vp;
                    o[dt] = __builtin_amdgcn_mfma_f32_16x16x32_bf16(ap, bv, o[dt], 0, 0, 0);
                }
            }
        }
    }

    const int bb = bh >> 4, hh = bh & 15;
#pragma unroll
    for (int i = 0; i < 4; ++i) {
        const float inv = 1.0f / fmaxf(l_i[i], 1e-20f);
        const int t = qrow0 + quad * 4 + i;
        u16* op = out + ((size_t)(bb * 4096 + t)) * 1024 + hh * 64;
#pragma unroll
        for (int dt = 0; dt < 4; ++dt) op[dt * 16 + colq] = f2bf(o[dt][i] * inv);
    }
}

// ---------------------------------------------------------------------------
extern "C" void kernel_launch(void* const* d_in, const int* in_sizes, int n_in,
                              void* d_out, int out_size, void* d_ws, size_t ws_size,
                              hipStream_t stream)
{
    const float* x      = (const float*)d_in[0];
    const float* ln1_w  = (const float*)d_in[1];
    const float* ln1_b  = (const float*)d_in[2];
    const float* qkv_w  = (const float*)d_in[3];
    const float* qkv_b  = (const float*)d_in[4];
    const float* proj_w = (const float*)d_in[5];
    const float* proj_b = (const float*)d_in[6];
    const float* ln2_w  = (const float*)d_in[7];
    const float* ln2_b  = (const float*)d_in[8];
    const float* fc1_w  = (const float*)d_in[9];
    const float* fc1_b  = (const float*)d_in[10];
    const float* fc2_w  = (const float*)d_in[11];
    const float* fc2_b  = (const float*)d_in[12];
    float* outp = (float*)d_out;

    if (ws_size < 134217728u) return;
    char* ws = (char*)d_ws;
    u16* R0 = (u16*)(ws);               // all bf16 weights (25.2 MB)
    u16* R1 = (u16*)(ws + 33554432);    // Q  -> x2
    u16* R2 = (u16*)(ws + 67108864);    // K  -> h (with R3, 67 MB contiguous)
    u16* R3 = (u16*)(ws + 100663296);   // Vt -> h upper half
    u16* xnc    = (u16*)d_out;                        // xn   @ d_out[0    : 33.5M)
    u16* attn_o = (u16*)((char*)d_out + 33554432);    // attn @ d_out[33.5M: 67M), later yn

    u16* qkvwb = R0;
    u16* projwb = R0 + 3145728;
    u16* fc1wb = R0 + 4194304;
    u16* fc2wb = R0 + 8388608;
    u16* Qb = R1, *Kb = R2, *Vtb = R3;
    u16* x2 = R1;                       // Q dead after attn
    u16* yn = attn_o;                   // attn_o dead after proj
    u16* hb = R2;                       // K,Vt dead after attn: 67 MB contiguous

    // 1. weights f32 -> bf16
    cvt_kernel<<<3072, 256, 0, stream>>>(qkv_w, qkvwb, 3145728);
    cvt_kernel<<<1024, 256, 0, stream>>>(proj_w, projwb, 1048576);
    cvt_kernel<<<4096, 256, 0, stream>>>(fc1_w, fc1wb, 4194304);
    cvt_kernel<<<4096, 256, 0, stream>>>(fc2_w, fc2wb, 4194304);
    // 2. LN1: x -> xn
    ln_kernel<true><<<4096, 256, 0, stream>>>(x, ln1_w, ln1_b, xnc);
    // 3. qkv GEMM + scatter (768 blocks of 512)
    gemm256<0, 0, false><<<dim3(12, 64), 512, 0, stream>>>(xnc, qkvwb, qkv_b, nullptr, nullptr,
                                                           Qb, Kb, Vtb, 16384, 3072, 1024, 0);
    // 4. local attention -> attn_o
    attn_kernel<<<4096, 256, 0, stream>>>(Qb, Kb, Vtb, attn_o);
    // 5. proj + residual(x, f32) -> x2 (bf16)
    gemm256<1, 1, false><<<dim3(4, 64), 512, 0, stream>>>(attn_o, projwb, proj_b, x, nullptr,
                                                          x2, nullptr, nullptr, 16384, 1024, 1024, 0);
    // 6. LN2: x2 -> yn
    ln_kernel<false><<<4096, 256, 0, stream>>>(x2, ln2_w, ln2_b, yn);
    // 7. FFN in 2 M-chunks of 8192 rows; h (67 MB) in R2+R3.
    for (int ci = 0; ci < 2; ++ci) {
        const size_t off = (size_t)ci * 8192 * 1024;
        gemm256<2, 0, false><<<dim3(16, 32), 512, 0, stream>>>(yn + off, fc1wb, fc1_b, nullptr, nullptr,
                                                               hb, nullptr, nullptr, 8192, 4096, 1024, 0);
        gemm256<1, 2, true><<<dim3(4, 32), 512, 0, stream>>>(hb, fc2wb, fc2_b, nullptr, x2 + off,
                                                             outp + off, nullptr, nullptr, 8192, 1024, 4096, 0);
    }
}